// Round 1
// baseline (2585.686 us; speedup 1.0000x reference)
//
#include <hip/hip_runtime.h>
#include <hip/hip_bf16.h>

// SAM2 MultiScale Block, fp32 baseline (round 0: correctness + structure).
// DIM=112, DIM_OUT=224, HEADS=4, HD=56, WS=8, QS=2, MLP_DIM=896
// x: (8,128,128,112) -> out: (8,64,64,224) fp32
//
// ws layout: hs (131072x112 f32 = 58,720,256 B) | hs2 (32768x224 f32 = 29,360,128 B)

#define NROWS   131072      // 8*128*128
#define NTOK    32768       // 8*64*64
#define SCALE_A 0.13363062095621219f  // 56^-0.5

// ---------------------------------------------------------------- LN1
__global__ __launch_bounds__(256) void ln1_kernel(
    const float* __restrict__ x, const float* __restrict__ g,
    const float* __restrict__ b, float* __restrict__ hs) {
  int row  = blockIdx.x * 4 + (threadIdx.x >> 6);
  int lane = threadIdx.x & 63;
  const float* rp = x + (size_t)row * 112;
  float v0 = rp[lane];
  float v1 = (lane < 48) ? rp[64 + lane] : 0.f;
  float s = v0 + v1;
  #pragma unroll
  for (int off = 32; off; off >>= 1) s += __shfl_down(s, off);
  s = __shfl(s, 0);
  float mean = s * (1.f / 112.f);
  float d0 = v0 - mean;
  float d1 = (lane < 48) ? (v1 - mean) : 0.f;
  float s2 = d0 * d0 + d1 * d1;
  #pragma unroll
  for (int off = 32; off; off >>= 1) s2 += __shfl_down(s2, off);
  s2 = __shfl(s2, 0);
  float rs = rsqrtf(s2 * (1.f / 112.f) + 1e-6f);
  float* op = hs + (size_t)row * 112;
  op[lane] = d0 * rs * g[lane] + b[lane];
  if (lane < 48) op[64 + lane] = d1 * rs * g[64 + lane] + b[64 + lane];
}

// ------------------------------------------- res_proj + maxpool2 -> hs2
__global__ __launch_bounds__(256) void respool_kernel(
    const float* __restrict__ hs, const float* __restrict__ w,
    const float* __restrict__ bias, float* __restrict__ res) {
  int pix = blockIdx.x;                 // over 8*64*64
  int j = pix & 63, i = (pix >> 6) & 63, b = pix >> 12;
  __shared__ float in4[4][112];
  int tid = threadIdx.x;
  for (int e = tid; e < 448; e += 256) {
    int r = e / 112, c = e % 112;
    int gh = 2 * i + (r >> 1), gw = 2 * j + (r & 1);
    in4[r][c] = hs[(((size_t)b * 128 + gh) * 128 + gw) * 112 + c];
  }
  __syncthreads();
  if (tid < 224) {
    float a0, a1, a2, a3;
    a0 = a1 = a2 = a3 = bias[tid];
    for (int k = 0; k < 112; ++k) {
      float wv = w[k * 224 + tid];
      a0 = fmaf(in4[0][k], wv, a0);
      a1 = fmaf(in4[1][k], wv, a1);
      a2 = fmaf(in4[2][k], wv, a2);
      a3 = fmaf(in4[3][k], wv, a3);
    }
    res[(size_t)pix * 224 + tid] = fmaxf(fmaxf(a0, a1), fmaxf(a2, a3));
  }
}

// ------------------- windowed attention (qkv, pool-q, softmax, o, proj, +res)
__global__ __launch_bounds__(256) void attn_kernel(
    const float* __restrict__ hs, const float* __restrict__ qkv_w,
    const float* __restrict__ qkv_b, const float* __restrict__ proj_w,
    const float* __restrict__ proj_b, float* __restrict__ hs2) {
  int win = blockIdx.x;                 // 2048 windows
  int nw = win & 15, nh = (win >> 4) & 15, b = win >> 8;
  __shared__ float w_s[64][112];        // 28,672 B
  __shared__ float k_s[64][56];         // 14,336
  __shared__ float v_s[64][56];         // 14,336
  __shared__ float q_s[16][56];         //  3,584
  __shared__ float att[16][64];         //  4,096
  __shared__ float o_all[16][224];      // 14,336   total 79,360 B -> 2 blk/CU
  int tid = threadIdx.x;

  for (int e = tid; e < 64 * 112; e += 256) {
    int r = e / 112, c = e % 112;
    int gh = nh * 8 + (r >> 3), gw = nw * 8 + (r & 7);
    w_s[r][c] = hs[(((size_t)b * 128 + gh) * 128 + gw) * 112 + c];
  }
  __syncthreads();

  for (int h = 0; h < 4; ++h) {
    // k and v fragments (64x56 each)
    for (int e = tid; e < 2 * 64 * 56; e += 256) {
      int which = e / 3584;             // 0=k, 1=v
      int rr = (e % 3584) / 56, c = e % 56;
      int colw = 224 + which * 224 + h * 56 + c;
      float acc = qkv_b[colw];
      for (int kk = 0; kk < 112; ++kk)
        acc = fmaf(w_s[rr][kk], qkv_w[kk * 672 + colw], acc);
      if (which == 0) k_s[rr][c] = acc; else v_s[rr][c] = acc;
    }
    // pooled q (16x56): max over 2x2 token block, bias added before max
    for (int e = tid; e < 16 * 56; e += 256) {
      int p = e / 56, c = e % 56;
      int r2 = p >> 2, c2 = p & 3;
      int row0 = 16 * r2 + 2 * c2;      // rows: row0, +1, +8, +9
      int colw = h * 56 + c;
      float bq = qkv_b[colw];
      float a0 = bq, a1 = bq, a2 = bq, a3 = bq;
      for (int kk = 0; kk < 112; ++kk) {
        float wv = qkv_w[kk * 672 + colw];
        a0 = fmaf(w_s[row0][kk], wv, a0);
        a1 = fmaf(w_s[row0 + 1][kk], wv, a1);
        a2 = fmaf(w_s[row0 + 8][kk], wv, a2);
        a3 = fmaf(w_s[row0 + 9][kk], wv, a3);
      }
      q_s[p][c] = fmaxf(fmaxf(a0, a1), fmaxf(a2, a3));
    }
    __syncthreads();
    // scores (16x64)
    for (int e = tid; e < 16 * 64; e += 256) {
      int p = e / 64, jj = e % 64;
      float acc = 0.f;
      for (int c = 0; c < 56; ++c) acc = fmaf(q_s[p][c], k_s[jj][c], acc);
      att[p][jj] = acc * SCALE_A;
    }
    __syncthreads();
    // softmax over 64 keys, one thread per row (16 rows, tiny)
    if (tid < 16) {
      float m = -1e30f;
      for (int jj = 0; jj < 64; ++jj) m = fmaxf(m, att[tid][jj]);
      float s = 0.f;
      for (int jj = 0; jj < 64; ++jj) { float ev = __expf(att[tid][jj] - m); att[tid][jj] = ev; s += ev; }
      float inv = 1.f / s;
      for (int jj = 0; jj < 64; ++jj) att[tid][jj] *= inv;
    }
    __syncthreads();
    // o = att @ v  -> o_all columns [h*56, h*56+56)
    for (int e = tid; e < 16 * 56; e += 256) {
      int p = e / 56, c = e % 56;
      float acc = 0.f;
      for (int jj = 0; jj < 64; ++jj) acc = fmaf(att[p][jj], v_s[jj][c], acc);
      o_all[p][h * 56 + c] = acc;
    }
    __syncthreads();  // protects k_s/v_s/q_s/att for next head, o_all for proj
  }

  // attn_proj + residual add into hs2
  for (int e = tid; e < 16 * 224; e += 256) {
    int p = e / 224, c = e % 224;
    float acc = proj_b[c];
    for (int kk = 0; kk < 224; ++kk)
      acc = fmaf(o_all[p][kk], proj_w[kk * 224 + c], acc);
    int r2 = p >> 2, c2 = p & 3;
    size_t pix = ((size_t)b * 64 + nh * 4 + r2) * 64 + (nw * 4 + c2);
    hs2[pix * 224 + c] += acc;
  }
}

// ---------------------- fused LN2 + mlp1 + GELU(exact) + mlp2 + residual
__global__ __launch_bounds__(256) void mlp_kernel(
    const float* __restrict__ hs2, const float* __restrict__ g2,
    const float* __restrict__ b2, const float* __restrict__ w1,
    const float* __restrict__ b1, const float* __restrict__ w2,
    const float* __restrict__ b2b, float* __restrict__ out) {
  int blk = blockIdx.x;                 // 2048 blocks x 16 tokens
  int tid = threadIdx.x;
  __shared__ float ln[16][224];         // 14,336 B (staging then normalized)
  __shared__ float hid[16][896];        // 57,344 B
  __shared__ float mv[16][2];           // total 71,808 B -> 2 blk/CU
  size_t base = (size_t)blk * 16 * 224;

  for (int e = tid; e < 16 * 224; e += 256) ln[e / 224][e % 224] = hs2[base + e];
  __syncthreads();
  {
    // 4 waves x 4 tokens; 16 lanes per token
    int wv = tid >> 6, lane = tid & 63;
    int t = wv * 4 + (lane >> 4), l16 = lane & 15;
    float s = 0.f;
    for (int c = l16; c < 224; c += 16) s += ln[t][c];
    #pragma unroll
    for (int off = 8; off; off >>= 1) s += __shfl_xor(s, off, 16);
    float mean = s * (1.f / 224.f);
    float s2 = 0.f;
    for (int c = l16; c < 224; c += 16) { float d = ln[t][c] - mean; s2 = fmaf(d, d, s2); }
    #pragma unroll
    for (int off = 8; off; off >>= 1) s2 += __shfl_xor(s2, off, 16);
    if (l16 == 0) { mv[t][0] = mean; mv[t][1] = rsqrtf(s2 * (1.f / 224.f) + 1e-6f); }
  }
  __syncthreads();
  for (int e = tid; e < 16 * 224; e += 256) {
    int t = e / 224, c = e % 224;
    ln[t][c] = (ln[t][c] - mv[t][0]) * mv[t][1] * g2[c] + b2[c];
  }
  __syncthreads();
  // mlp1 + exact gelu; 16-token register blocking: 16 FMA per weight load
  for (int cg = 0; cg < 4; ++cg) {
    int jc = cg * 256 + tid;
    if (jc < 896) {
      float acc[16];
      float bb = b1[jc];
      #pragma unroll
      for (int t = 0; t < 16; ++t) acc[t] = bb;
      for (int kk = 0; kk < 224; ++kk) {
        float wv = w1[kk * 896 + jc];
        #pragma unroll
        for (int t = 0; t < 16; ++t) acc[t] = fmaf(ln[t][kk], wv, acc[t]);
      }
      #pragma unroll
      for (int t = 0; t < 16; ++t) {
        float xx = acc[t];
        hid[t][jc] = 0.5f * xx * (1.f + erff(xx * 0.70710678118f));
      }
    }
  }
  __syncthreads();
  // mlp2 + residual
  if (tid < 224) {
    float acc[16];
    float bb = b2b[tid];
    #pragma unroll
    for (int t = 0; t < 16; ++t) acc[t] = bb;
    for (int kk = 0; kk < 896; ++kk) {
      float wv = w2[kk * 224 + tid];
      #pragma unroll
      for (int t = 0; t < 16; ++t) acc[t] = fmaf(hid[t][kk], wv, acc[t]);
    }
    #pragma unroll
    for (int t = 0; t < 16; ++t)
      out[base + t * 224 + tid] = hs2[base + t * 224 + tid] + acc[t];
  }
}

extern "C" void kernel_launch(void* const* d_in, const int* in_sizes, int n_in,
                              void* d_out, int out_size, void* d_ws, size_t ws_size,
                              hipStream_t stream) {
  const float* x     = (const float*)d_in[0];
  const float* ln1g  = (const float*)d_in[1];
  const float* ln1b  = (const float*)d_in[2];
  const float* qkvw  = (const float*)d_in[3];
  const float* qkvb  = (const float*)d_in[4];
  const float* apw   = (const float*)d_in[5];
  const float* apb   = (const float*)d_in[6];
  const float* rpw   = (const float*)d_in[7];
  const float* rpb   = (const float*)d_in[8];
  const float* ln2g  = (const float*)d_in[9];
  const float* ln2b  = (const float*)d_in[10];
  const float* w1    = (const float*)d_in[11];
  const float* b1    = (const float*)d_in[12];
  const float* w2    = (const float*)d_in[13];
  const float* b2    = (const float*)d_in[14];
  float* out = (float*)d_out;
  float* hs  = (float*)d_ws;            // 14,680,064 f32
  float* hs2 = hs + 14680064;           //  7,340,032 f32

  ln1_kernel<<<NROWS / 4, 256, 0, stream>>>(x, ln1g, ln1b, hs);
  respool_kernel<<<NTOK, 256, 0, stream>>>(hs, rpw, rpb, hs2);
  attn_kernel<<<2048, 256, 0, stream>>>(hs, qkvw, qkvb, apw, apb, hs2);
  mlp_kernel<<<2048, 256, 0, stream>>>(hs2, ln2g, ln2b, w1, b1, w2, b2, out);
}

// Round 2
// 455.034 us; speedup vs baseline: 5.6824x; 5.6824x over previous
//
#include <hip/hip_runtime.h>
#include <hip/hip_bf16.h>
#include <math.h>

// SAM2 MultiScale Block — round 1: all GEMMs on bf16 MFMA (16x16x32).
// DIM=112(K pad 128), DIM_OUT=224, HEADS=4, HD=56, WS=8, QS=2, MLP=896
//
// ws layout (bytes):
//   hs_bf  @ 0          : 131072x112 bf16 = 29,360,128
//   hs2    @ 29,360,128 : 32768x224 f32   = 29,360,128
//   o_bf   @ 58,720,256 : 32768x224 bf16  = 14,680,064
//   wT     @ 73,400,320 : transposed bf16 weights, 584,192 elems
//     qkvT [672][136] @ +0        rpT [224][136] @ +91392
//     apT  [224][232] @ +121856   m1T [896][232] @ +173824
//     m2T  [224][904] @ +381696

#define SCALE_A 0.13363062095621219f  // 56^-0.5

typedef __attribute__((ext_vector_type(8))) short short8;
typedef __attribute__((ext_vector_type(4))) float f32x4;

__device__ inline short f2bf(float x) {
  union { float f; unsigned u; } v; v.f = x;
  unsigned r = v.u + 0x7fff + ((v.u >> 16) & 1);
  return (short)(r >> 16);
}

// ---------------------------------------------------------------- weight cast
__global__ void cast_w_kernel(const float* __restrict__ qkv_w,
                              const float* __restrict__ rp_w,
                              const float* __restrict__ ap_w,
                              const float* __restrict__ m1_w,
                              const float* __restrict__ m2_w,
                              short* __restrict__ wT) {
  int tid = blockIdx.x * blockDim.x + threadIdx.x;
  int stride = gridDim.x * blockDim.x;
  for (int e = tid; e < 672 * 136; e += stride) {
    int n = e / 136, k = e % 136;
    wT[e] = (k < 112) ? f2bf(qkv_w[k * 672 + n]) : (short)0;
  }
  for (int e = tid; e < 224 * 136; e += stride) {
    int n = e / 136, k = e % 136;
    wT[91392 + e] = (k < 112) ? f2bf(rp_w[k * 224 + n]) : (short)0;
  }
  for (int e = tid; e < 224 * 232; e += stride) {
    int n = e / 232, k = e % 232;
    wT[121856 + e] = (k < 224) ? f2bf(ap_w[k * 224 + n]) : (short)0;
  }
  for (int e = tid; e < 896 * 232; e += stride) {
    int n = e / 232, k = e % 232;
    wT[173824 + e] = (k < 224) ? f2bf(m1_w[k * 896 + n]) : (short)0;
  }
  for (int e = tid; e < 224 * 904; e += stride) {
    int n = e / 904, k = e % 904;
    wT[381696 + e] = (k < 896) ? f2bf(m2_w[k * 224 + n]) : (short)0;
  }
}

// ---------------------------------------------------------------- LN1 -> bf16
__global__ __launch_bounds__(256) void ln1_kernel(
    const float* __restrict__ x, const float* __restrict__ g,
    const float* __restrict__ b, short* __restrict__ hs) {
  int row = blockIdx.x * 4 + (threadIdx.x >> 6);
  int lane = threadIdx.x & 63;
  const float* rp = x + (size_t)row * 112;
  float v0 = rp[lane];
  float v1 = (lane < 48) ? rp[64 + lane] : 0.f;
  float s = v0 + v1;
  #pragma unroll
  for (int off = 32; off; off >>= 1) s += __shfl_down(s, off);
  s = __shfl(s, 0);
  float mean = s * (1.f / 112.f);
  float d0 = v0 - mean;
  float d1 = (lane < 48) ? (v1 - mean) : 0.f;
  float s2 = d0 * d0 + d1 * d1;
  #pragma unroll
  for (int off = 32; off; off >>= 1) s2 += __shfl_down(s2, off);
  s2 = __shfl(s2, 0);
  float rs = rsqrtf(s2 * (1.f / 112.f) + 1e-6f);
  short* op = hs + (size_t)row * 112;
  op[lane] = f2bf(d0 * rs * g[lane] + b[lane]);
  if (lane < 48) op[64 + lane] = f2bf(d1 * rs * g[64 + lane] + b[64 + lane]);
}

// -------------------------------------- res_proj + maxpool2 (MFMA) -> hs2
// Block: 16 output pixels (same row). A rows in pool-group order: m = p*4+r,
// so each lane's 4 C-regs are exactly one 2x2 pool group.
__global__ __launch_bounds__(256) void respool_kernel(
    const short* __restrict__ hs, const short* __restrict__ rpT,
    const float* __restrict__ bias, float* __restrict__ hs2) {
  __shared__ alignas(16) short w_s[64 * 136];
  int blk = blockIdx.x;  // 2048
  int tid = threadIdx.x;
  for (int e = tid; e < 1024; e += 256) {
    int m = e >> 4, c = e & 15;
    short8* dst = (short8*)&w_s[m * 136 + c * 8];
    if (c < 14) {
      int p = m >> 2, r = m & 3;
      int pix = blk * 16 + p;
      int bb = pix >> 12, ii = (pix >> 6) & 63, jj = pix & 63;
      size_t token = ((size_t)(bb * 128 + 2 * ii + (r >> 1))) * 128 + 2 * jj + (r & 1);
      *dst = *(const short8*)(hs + token * 112 + c * 8);
    } else {
      short8 z = {0, 0, 0, 0, 0, 0, 0, 0};
      *dst = z;
    }
  }
  __syncthreads();
  int wave = tid >> 6, lane = tid & 63, lrow = lane & 15, lq = lane >> 4;
  for (int nt = 0; nt < 14; ++nt) {
    int col = nt * 16 + lrow;
    f32x4 acc = {0.f, 0.f, 0.f, 0.f};
    #pragma unroll
    for (int kt = 0; kt < 4; ++kt) {
      short8 a = *(const short8*)&w_s[(wave * 16 + lrow) * 136 + kt * 32 + lq * 8];
      short8 bf = *(const short8*)(rpT + col * 136 + kt * 32 + lq * 8);
      acc = __builtin_amdgcn_mfma_f32_16x16x32_bf16(a, bf, acc, 0, 0, 0);
    }
    float mx = fmaxf(fmaxf(acc[0], acc[1]), fmaxf(acc[2], acc[3])) + bias[col];
    int p = wave * 4 + lq;
    hs2[(size_t)(blk * 16 + p) * 224 + col] = mx;
  }
}

// ------------------- fused windowed attention (MFMA qkv / scores / PV)
__global__ __launch_bounds__(256) void attn_kernel(
    const short* __restrict__ hs, const short* __restrict__ qkvT,
    const float* __restrict__ qkv_b, short* __restrict__ o_bf) {
  __shared__ alignas(16) short w_s[64 * 136];   // window tokens, pool order
  __shared__ alignas(16) short k_s[64 * 72];    // keys x hd (cols 56..63 = 0)
  __shared__ alignas(16) short vT_s[64 * 72];   // hd x keys (transposed v)
  __shared__ alignas(16) short q_s[16 * 72];    // pooled q * scale
  __shared__ alignas(16) float att[16 * 68];
  int win = blockIdx.x;                         // 2048
  int nw = win & 15, nh = (win >> 4) & 15, b = win >> 8;
  int tid = threadIdx.x;
  int wave = tid >> 6, lane = tid & 63, lrow = lane & 15, lq = lane >> 4;

  for (int e = tid; e < 1024; e += 256) {
    int m = e >> 4, c = e & 15;
    short8* dst = (short8*)&w_s[m * 136 + c * 8];
    if (c < 14) {
      int p = m >> 2, r = m & 3;
      int tr = (p >> 2) * 2 + (r >> 1), tc = (p & 3) * 2 + (r & 1);
      size_t token = ((size_t)(b * 128 + nh * 8 + tr)) * 128 + (nw * 8 + tc);
      *dst = *(const short8*)(hs + token * 112 + c * 8);
    } else {
      short8 z = {0, 0, 0, 0, 0, 0, 0, 0};
      *dst = z;
    }
  }
  for (int e = tid; e < 512; e += 256) k_s[(e >> 3) * 72 + 56 + (e & 7)] = 0;
  if (tid < 128) q_s[(tid >> 3) * 72 + 56 + (tid & 7)] = 0;
  __syncthreads();

  for (int h = 0; h < 4; ++h) {
    // qkv projection for this head; col list = [q 0..55 | k 56..111 | v 112..167]
    for (int nt = 0; nt < 11; ++nt) {
      int cl = nt * 16 + lrow;
      int bcol;
      if (cl < 56)       bcol = h * 56 + cl;
      else if (cl < 112) bcol = 224 + h * 56 + (cl - 56);
      else if (cl < 168) bcol = 448 + h * 56 + (cl - 112);
      else               bcol = 448 + h * 56 + 55;  // dummy, discarded
      f32x4 acc = {0.f, 0.f, 0.f, 0.f};
      #pragma unroll
      for (int kt = 0; kt < 4; ++kt) {
        short8 a = *(const short8*)&w_s[(wave * 16 + lrow) * 136 + kt * 32 + lq * 8];
        short8 bf = *(const short8*)(qkvT + bcol * 136 + kt * 32 + lq * 8);
        acc = __builtin_amdgcn_mfma_f32_16x16x32_bf16(a, bf, acc, 0, 0, 0);
      }
      float bias = qkv_b[bcol];
      if (cl < 56) {
        // 4 regs = one 2x2 pool group -> pooled q, scale folded in
        float mx = fmaxf(fmaxf(acc[0], acc[1]), fmaxf(acc[2], acc[3])) + bias;
        int p = wave * 4 + lq;
        q_s[p * 72 + cl] = f2bf(mx * SCALE_A);
      } else if (cl < 112) {
        #pragma unroll
        for (int r = 0; r < 4; ++r) {
          int m = wave * 16 + lq * 4 + r;
          k_s[m * 72 + (cl - 56)] = f2bf(acc[r] + bias);
        }
      } else if (cl < 168) {
        #pragma unroll
        for (int r = 0; r < 4; ++r) {
          int m = wave * 16 + lq * 4 + r;
          vT_s[(cl - 112) * 72 + m] = f2bf(acc[r] + bias);
        }
      }
    }
    __syncthreads();
    // scores: wave handles keys [wave*16, +16); K=56 padded to 64 (zeros)
    {
      f32x4 acc = {0.f, 0.f, 0.f, 0.f};
      #pragma unroll
      for (int kt = 0; kt < 2; ++kt) {
        short8 a = *(const short8*)&q_s[lrow * 72 + kt * 32 + lq * 8];
        short8 bf = *(const short8*)&k_s[(wave * 16 + lrow) * 72 + kt * 32 + lq * 8];
        acc = __builtin_amdgcn_mfma_f32_16x16x32_bf16(a, bf, acc, 0, 0, 0);
      }
      #pragma unroll
      for (int r = 0; r < 4; ++r)
        att[(lq * 4 + r) * 68 + wave * 16 + lrow] = acc[r];
    }
    __syncthreads();
    if (tid < 16) {
      float m = -1e30f;
      for (int j = 0; j < 64; ++j) m = fmaxf(m, att[tid * 68 + j]);
      float s = 0.f;
      for (int j = 0; j < 64; ++j) {
        float e = __expf(att[tid * 68 + j] - m);
        att[tid * 68 + j] = e; s += e;
      }
      float inv = 1.f / s;
      for (int j = 0; j < 64; ++j) att[tid * 68 + j] *= inv;
    }
    __syncthreads();
    // PV: wave handles out cols [wave*16, +16); K=64 keys
    {
      int col = wave * 16 + lrow;
      f32x4 acc = {0.f, 0.f, 0.f, 0.f};
      #pragma unroll
      for (int kt = 0; kt < 2; ++kt) {
        const float* ap = &att[lrow * 68 + kt * 32 + lq * 8];
        short8 a;
        #pragma unroll
        for (int j = 0; j < 8; ++j) a[j] = f2bf(ap[j]);
        short8 bf = *(const short8*)&vT_s[col * 72 + kt * 32 + lq * 8];
        acc = __builtin_amdgcn_mfma_f32_16x16x32_bf16(a, bf, acc, 0, 0, 0);
      }
      if (col < 56) {
        #pragma unroll
        for (int r = 0; r < 4; ++r) {
          int p = lq * 4 + r;
          size_t token = ((size_t)(b * 64 + nh * 4 + (p >> 2))) * 64 + (nw * 4 + (p & 3));
          o_bf[token * 224 + h * 56 + col] = f2bf(acc[r]);
        }
      }
    }
    __syncthreads();
  }
}

// ---------------------------- attn_proj GEMM + bias + residual into hs2
__global__ __launch_bounds__(256) void aproj_kernel(
    const short* __restrict__ o_bf, const short* __restrict__ apT,
    const float* __restrict__ apb, float* __restrict__ hs2) {
  __shared__ alignas(16) short o_s[64 * 232];
  int blk = blockIdx.x;  // 512 x 64 tokens
  int tid = threadIdx.x;
  for (int e = tid; e < 64 * 28; e += 256) {
    int m = e / 28, c = e % 28;
    *(short8*)&o_s[m * 232 + c * 8] =
        *(const short8*)(o_bf + ((size_t)blk * 64 + m) * 224 + c * 8);
  }
  __syncthreads();
  int wave = tid >> 6, lane = tid & 63, lrow = lane & 15, lq = lane >> 4;
  for (int nt = 0; nt < 14; ++nt) {
    int col = nt * 16 + lrow;
    f32x4 acc = {0.f, 0.f, 0.f, 0.f};
    #pragma unroll
    for (int kt = 0; kt < 7; ++kt) {
      short8 a = *(const short8*)&o_s[(wave * 16 + lrow) * 232 + kt * 32 + lq * 8];
      short8 bf = *(const short8*)(apT + col * 232 + kt * 32 + lq * 8);
      acc = __builtin_amdgcn_mfma_f32_16x16x32_bf16(a, bf, acc, 0, 0, 0);
    }
    float bias = apb[col];
    #pragma unroll
    for (int r = 0; r < 4; ++r) {
      size_t idx = ((size_t)blk * 64 + wave * 16 + lq * 4 + r) * 224 + col;
      hs2[idx] += acc[r] + bias;
    }
  }
}

// ------------- fused LN2 + mlp1(MFMA) + GELU + mlp2(MFMA) + residual
__global__ __launch_bounds__(256) void mlp_kernel(
    const float* __restrict__ hs2, const float* __restrict__ g2,
    const float* __restrict__ b2, const short* __restrict__ m1T,
    const float* __restrict__ b1, const short* __restrict__ m2T,
    const float* __restrict__ b2b, float* __restrict__ out) {
  __shared__ alignas(16) short ln_s[32 * 232];
  __shared__ alignas(16) short hid_s[32 * 904];
  __shared__ float red[32][2];
  int blk = blockIdx.x;  // 1024 x 32 tokens
  int tid = threadIdx.x;
  size_t base = (size_t)blk * 32 * 224;
  {
    int row = tid >> 3, l8 = tid & 7;
    const float* rp = hs2 + base + (size_t)row * 224;
    float s = 0.f;
    for (int c = l8; c < 224; c += 8) s += rp[c];
    #pragma unroll
    for (int off = 4; off; off >>= 1) s += __shfl_xor(s, off, 8);
    float mean = s * (1.f / 224.f);
    float s2 = 0.f;
    for (int c = l8; c < 224; c += 8) { float d = rp[c] - mean; s2 = fmaf(d, d, s2); }
    #pragma unroll
    for (int off = 4; off; off >>= 1) s2 += __shfl_xor(s2, off, 8);
    if (l8 == 0) { red[row][0] = mean; red[row][1] = rsqrtf(s2 * (1.f / 224.f) + 1e-6f); }
  }
  __syncthreads();
  for (int e = tid; e < 32 * 224; e += 256) {
    int m = e / 224, c = e % 224;
    float v = hs2[base + (size_t)m * 224 + c];
    ln_s[m * 232 + c] = f2bf((v - red[m][0]) * red[m][1] * g2[c] + b2[c]);
  }
  __syncthreads();
  int wave = tid >> 6, lane = tid & 63, lrow = lane & 15, lq = lane >> 4;
  int mt = wave & 1, nhf = wave >> 1;
  for (int t = 0; t < 28; ++t) {
    int col = (nhf * 28 + t) * 16 + lrow;
    f32x4 acc = {0.f, 0.f, 0.f, 0.f};
    #pragma unroll
    for (int kt = 0; kt < 7; ++kt) {
      short8 a = *(const short8*)&ln_s[(mt * 16 + lrow) * 232 + kt * 32 + lq * 8];
      short8 bf = *(const short8*)(m1T + col * 232 + kt * 32 + lq * 8);
      acc = __builtin_amdgcn_mfma_f32_16x16x32_bf16(a, bf, acc, 0, 0, 0);
    }
    float bias = b1[col];
    #pragma unroll
    for (int r = 0; r < 4; ++r) {
      float xx = acc[r] + bias;
      float gl = 0.5f * xx * (1.f + erff(xx * 0.70710678118f));
      hid_s[(mt * 16 + lq * 4 + r) * 904 + col] = f2bf(gl);
    }
  }
  __syncthreads();
  for (int t = 0; t < 7; ++t) {
    int col = (nhf * 7 + t) * 16 + lrow;
    f32x4 acc = {0.f, 0.f, 0.f, 0.f};
    for (int kt = 0; kt < 28; ++kt) {
      short8 a = *(const short8*)&hid_s[(mt * 16 + lrow) * 904 + kt * 32 + lq * 8];
      short8 bf = *(const short8*)(m2T + col * 904 + kt * 32 + lq * 8);
      acc = __builtin_amdgcn_mfma_f32_16x16x32_bf16(a, bf, acc, 0, 0, 0);
    }
    float bias = b2b[col];
    #pragma unroll
    for (int r = 0; r < 4; ++r) {
      size_t idx = base + (size_t)(mt * 16 + lq * 4 + r) * 224 + col;
      out[idx] = hs2[idx] + acc[r] + bias;
    }
  }
}

extern "C" void kernel_launch(void* const* d_in, const int* in_sizes, int n_in,
                              void* d_out, int out_size, void* d_ws, size_t ws_size,
                              hipStream_t stream) {
  const float* x    = (const float*)d_in[0];
  const float* ln1g = (const float*)d_in[1];
  const float* ln1b = (const float*)d_in[2];
  const float* qkvw = (const float*)d_in[3];
  const float* qkvb = (const float*)d_in[4];
  const float* apw  = (const float*)d_in[5];
  const float* apb  = (const float*)d_in[6];
  const float* rpw  = (const float*)d_in[7];
  const float* rpb  = (const float*)d_in[8];
  const float* ln2g = (const float*)d_in[9];
  const float* ln2b = (const float*)d_in[10];
  const float* w1   = (const float*)d_in[11];
  const float* b1   = (const float*)d_in[12];
  const float* w2   = (const float*)d_in[13];
  const float* b2   = (const float*)d_in[14];
  float* out = (float*)d_out;

  short* hs_bf = (short*)d_ws;
  float* hs2   = (float*)((char*)d_ws + 29360128);
  short* o_bf  = (short*)((char*)d_ws + 58720256);
  short* wT    = (short*)((char*)d_ws + 73400320);

  cast_w_kernel<<<512, 256, 0, stream>>>(qkvw, rpw, apw, w1, w2, wT);
  ln1_kernel<<<32768, 256, 0, stream>>>(x, ln1g, ln1b, hs_bf);
  respool_kernel<<<2048, 256, 0, stream>>>(hs_bf, wT + 91392, rpb, hs2);
  attn_kernel<<<2048, 256, 0, stream>>>(hs_bf, wT, qkvb, o_bf);
  aproj_kernel<<<512, 256, 0, stream>>>(o_bf, wT + 121856, apb, hs2);
  mlp_kernel<<<1024, 256, 0, stream>>>(hs2, ln2g, ln2b, wT + 173824, b1,
                                       wT + 381696, b2, out);
}